// Round 8
// baseline (925.915 us; speedup 1.0000x reference)
//
#include <hip/hip_runtime.h>
#include <cstdint>
#include <cstddef>

// Problem constants
#define NBATCH   8192
#define DFEAT    256
#define DCONV    128
#define NCLASS   5
#define NEDGE    500000
#define NUSERS   100000
#define BN_EPS   1e-3f
#define NBUCKET  128       // dst buckets of 64 rows each
#define BROWS    64
#define CAP      4608      // fixed bucket capacity (mean 3906, +11 sigma)

typedef unsigned short u16;
typedef unsigned long long u64;
typedef short bf16x8_t __attribute__((ext_vector_type(8)));
typedef float f32x4_t  __attribute__((ext_vector_type(4)));

__device__ __forceinline__ u16 f2bf(float x) {
    unsigned u = __float_as_uint(x);
    u += 0x7FFF + ((u >> 16) & 1);
    return (u16)(u >> 16);
}
__device__ __forceinline__ float bf2f(u16 h) {
    return __uint_as_float(((unsigned)h) << 16);
}

// ============================================================================
// bf16 MFMA GEMM core: tile 64x64, block = 256 threads (4 waves), K-step 32.
//   C/D: lane l, reg r -> row = (l>>4)*4 + r, col = l&15   (m89-verified)
// ============================================================================
__device__ __forceinline__ void mfma_tiles(
    const u16* __restrict__ A, int lda, const int* __restrict__ gather,
    const u16* __restrict__ BT, int K,
    int tileM, int tileN, u16* As, u16* Bs, f32x4_t acc[4])
{
    const int t    = threadIdx.x;
    const int rowi = t >> 2;
    const int kc   = t & 3;
    const int w    = t >> 6;
    const int lane = t & 63;

    int ar = gather ? gather[tileM + rowi] : (tileM + rowi);
    const u16* Ap = A  + (size_t)ar * lda + kc * 8;
    const u16* Bp = BT + (size_t)(tileN + rowi) * K + kc * 8;
    u16* Aw = As + (size_t)(((rowi >> 4) * 64) + (rowi & 15) + 16 * kc) * 8;
    u16* Bw = Bs + (size_t)(((rowi >> 4) * 64) + (rowi & 15) + 16 * kc) * 8;
    const u16* Ar = As + (size_t)(w * 64 + lane) * 8;

    for (int k0 = 0; k0 < K; k0 += 32) {
        __syncthreads();
        *(uint4*)Aw = *(const uint4*)(Ap + k0);
        *(uint4*)Bw = *(const uint4*)(Bp + k0);
        __syncthreads();
        bf16x8_t av = *(const bf16x8_t*)Ar;
        #pragma unroll
        for (int nb = 0; nb < 4; ++nb) {
            bf16x8_t bv = *(const bf16x8_t*)(Bs + (size_t)(nb * 64 + lane) * 8);
            acc[nb] = __builtin_amdgcn_mfma_f32_16x16x32_bf16(av, bv, acc[nb], 0, 0, 0);
        }
    }
}

__device__ __forceinline__ void epilogue(
    f32x4_t acc[4], int tileM, int tileN,
    const float* __restrict__ bias, const float* __restrict__ bn, int bn_ld,
    int relu, u16* __restrict__ out_bf, float* __restrict__ out_f32, int ldc)
{
    const int t = threadIdx.x, w = t >> 6, lane = t & 63;
    const int row0 = tileM + w * 16 + (lane >> 4) * 4;
    #pragma unroll
    for (int nb = 0; nb < 4; ++nb) {
        int col = tileN + nb * 16 + (lane & 15);
        float g = 1.f, be = 0.f, mu = 0.f, va = 1.f, bs = 0.f;
        if (bn)   { g = bn[col]; be = bn[bn_ld + col]; mu = bn[2 * bn_ld + col]; va = bn[3 * bn_ld + col]; }
        if (bias) bs = bias[col];
        #pragma unroll
        for (int r = 0; r < 4; ++r) {
            float x = acc[nb][r] + bs;
            if (bn)   x = g * (x - mu) * rsqrtf(va + BN_EPS) + be;
            if (relu) x = fmaxf(x, 0.f);
            size_t o = (size_t)(row0 + r) * ldc + col;
            if (out_bf) out_bf[o] = f2bf(x);
            else        out_f32[o] = x;
        }
    }
}

// f path, fused user(z=0)/item(z=1)
__global__ __launch_bounds__(256) void k_gemm_f(
    const u16* __restrict__ ubf, const u16* __restrict__ ibf,
    const int* __restrict__ uidx, const int* __restrict__ iidx,
    const u16* __restrict__ WTu, const u16* __restrict__ WTi,
    const float* __restrict__ bu, const float* __restrict__ bi,
    const float* __restrict__ bnu, const float* __restrict__ bni,
    u16* __restrict__ outu, u16* __restrict__ outi)
{
    __shared__ __align__(16) u16 As[2048], Bs[2048];
    f32x4_t z4 = {0.f, 0.f, 0.f, 0.f};
    f32x4_t acc[4] = {z4, z4, z4, z4};
    int z = blockIdx.z;
    const u16* feat = z ? ibf : ubf;
    const int* idx  = z ? iidx : uidx;
    const u16* WT   = z ? WTi : WTu;
    const float* bias = z ? bi : bu;
    const float* bn   = z ? bni : bnu;
    u16* out = z ? outi : outu;
    int tileM = blockIdx.x * 64, tileN = blockIdx.y * 64;
    mfma_tiles(feat, 256, idx, WT, 256, tileM, tileN, As, Bs, acc);
    epilogue(acc, tileM, tileN, bias, bn, 256, 1, out, nullptr, 256);
}

__global__ __launch_bounds__(256) void k_hproj(
    const u16* __restrict__ agg, const u16* __restrict__ WucT, const u16* __restrict__ WicT,
    const float* __restrict__ bn_hu, const float* __restrict__ bn_hi,
    u16* __restrict__ h_user, u16* __restrict__ h_item)
{
    __shared__ __align__(16) u16 As[2048], Bs[2048];
    f32x4_t z4 = {0.f, 0.f, 0.f, 0.f};
    f32x4_t acc[4] = {z4, z4, z4, z4};
    int cs = blockIdx.z, c = cs % NCLASS, side = cs / NCLASS;
    const u16* A  = agg + (size_t)cs * NBATCH * DFEAT;
    const u16* BT = (side ? WicT : WucT) + (size_t)c * DCONV * DFEAT;
    const float* bn = (side ? bn_hi : bn_hu) + c * DCONV;
    u16* out = (side ? h_item : h_user) + c * DCONV;
    int tileM = blockIdx.x * 64, tileN = blockIdx.y * 64;
    mfma_tiles(A, 256, nullptr, BT, 256, tileM, tileN, As, Bs, acc);
    epilogue(acc, tileM, tileN, nullptr, bn, NCLASS * DCONV, 1, out, nullptr, NCLASS * DCONV);
}

// embedding, fused user(z=0)/item(z=1), K = 256 + 640
__global__ __launch_bounds__(256) void k_emb(
    const u16* __restrict__ fu, const u16* __restrict__ fi,
    const u16* __restrict__ hu, const u16* __restrict__ hi,
    const u16* __restrict__ W2fTu, const u16* __restrict__ W2hTu,
    const u16* __restrict__ W2fTi, const u16* __restrict__ W2hTi,
    u16* __restrict__ embu, u16* __restrict__ embi)
{
    __shared__ __align__(16) u16 As[2048], Bs[2048];
    f32x4_t z4 = {0.f, 0.f, 0.f, 0.f};
    f32x4_t acc[4] = {z4, z4, z4, z4};
    int z = blockIdx.z;
    const u16* fbf  = z ? fi : fu;
    const u16* hbf  = z ? hi : hu;
    const u16* W2fT = z ? W2fTi : W2fTu;
    const u16* W2hT = z ? W2hTi : W2hTu;
    u16* emb = z ? embi : embu;
    int tileM = blockIdx.x * 64, tileN = blockIdx.y * 64;
    mfma_tiles(fbf, 256, nullptr, W2fT, 256, tileM, tileN, As, Bs, acc);
    mfma_tiles(hbf, NCLASS * DCONV, nullptr, W2hT, NCLASS * DCONV, tileM, tileN, As, Bs, acc);
    epilogue(acc, tileM, tileN, nullptr, nullptr, 0, 1, emb, nullptr, 256);
}

__global__ __launch_bounds__(256) void k_dec(
    const u16* __restrict__ emb, const u16* __restrict__ WdecT,
    float* __restrict__ t0, float* __restrict__ t1)
{
    __shared__ __align__(16) u16 As[2048], Bs[2048];
    f32x4_t z4 = {0.f, 0.f, 0.f, 0.f};
    f32x4_t acc[4] = {z4, z4, z4, z4};
    int zi = blockIdx.z;
    const u16* BT = WdecT + (size_t)zi * 256 * 256;
    float* out = zi ? t1 : t0;
    int tileM = blockIdx.x * 64, tileN = blockIdx.y * 64;
    mfma_tiles(emb, 256, nullptr, BT, 256, tileM, tileN, As, Bs, acc);
    epilogue(acc, tileM, tileN, nullptr, nullptr, 0, 0, nullptr, out, 256);
}

// ============================================================================
// fused prep: y=0..8 weight convert+transpose, y=9 Wdec, y=10 features (+bcur)
// ============================================================================
#define OFF_WFU   0
#define OFF_WFI   65536
#define OFF_WUC   131072
#define OFF_WIC   294912
#define OFF_W2FU  458752
#define OFF_W2HU  524288
#define OFF_W2FI  688128
#define OFF_W2HI  753664
#define OFF_WDEC  917504

__global__ __launch_bounds__(256) void cvt_all(
    const float* __restrict__ uf, const float* __restrict__ itf,
    u16* __restrict__ ubf, u16* __restrict__ ibf,
    const float* __restrict__ Wfu, const float* __restrict__ Wfi,
    const float* __restrict__ Wuc, const float* __restrict__ Wic,
    const float* __restrict__ W2fu, const float* __restrict__ W2hu,
    const float* __restrict__ W2fi, const float* __restrict__ W2hi,
    const float* __restrict__ Wdec, u16* __restrict__ wT,
    int* __restrict__ bcur)
{
    if (blockIdx.y == 10) {
        // feature tables fp32 -> bf16 (grid-stride over float4 chunks)
        if (blockIdx.x == 0) {
            for (int i = threadIdx.x; i < 10 * NBUCKET; i += 256)
                bcur[i] = (i & (NBUCKET - 1)) * CAP;
        }
        const size_t n4 = (size_t)NUSERS * DFEAT / 4;
        for (size_t i = (size_t)blockIdx.x * 256 + threadIdx.x; i < 2 * n4;
             i += (size_t)gridDim.x * 256) {
            bool u = i < n4;
            size_t j = u ? i : i - n4;
            float4 v = u ? ((const float4*)uf)[j] : ((const float4*)itf)[j];
            ushort4 o;
            o.x = f2bf(v.x); o.y = f2bf(v.y); o.z = f2bf(v.z); o.w = f2bf(v.w);
            ((ushort4*)(u ? ubf : ibf))[j] = o;
        }
        return;
    }
    const float* in; u16* out; int K, N, B;
    switch (blockIdx.y) {
        case 0: in = Wfu;  out = wT + OFF_WFU;  K = 256; N = 256; B = 1; break;
        case 1: in = Wfi;  out = wT + OFF_WFI;  K = 256; N = 256; B = 1; break;
        case 2: in = Wuc;  out = wT + OFF_WUC;  K = 256; N = 128; B = 5; break;
        case 3: in = Wic;  out = wT + OFF_WIC;  K = 256; N = 128; B = 5; break;
        case 4: in = W2fu; out = wT + OFF_W2FU; K = 256; N = 256; B = 1; break;
        case 5: in = W2hu; out = wT + OFF_W2HU; K = 640; N = 256; B = 1; break;
        case 6: in = W2fi; out = wT + OFF_W2FI; K = 256; N = 256; B = 1; break;
        case 7: in = W2hi; out = wT + OFF_W2HI; K = 640; N = 256; B = 1; break;
        default: in = Wdec; out = wT + OFF_WDEC; K = 256; N = 256; B = 2; break;
    }
    int total = B * K * N;
    for (int idx = blockIdx.x * 256 + threadIdx.x; idx < total; idx += 160 * 256) {
        int b = idx / (K * N);
        int r = idx - b * K * N;
        int n = r / K;
        int k = r - n * K;
        out[idx] = f2bf(in[(size_t)(b * K + k) * N + n]);
    }
}

// ============================================================================
// Bucketed graph aggregation (fixed-capacity regions, CAP edges each).
// partition: per-block LDS histogram -> one global atomicAdd per
//            (block,bucket) -> per-edge placement via LDS int cursors.
// spmm_sorted: block per (bucket, cs), 512 thr. In-LDS counting sort by
//            dst-low6 with PER-WAVE histograms and per-wave scatter cursors
//            (8x less LDS atomic contention than R6). Then wave w processes
//            rows [8w,8w+8): contiguous edge lists, each edge read once,
//            512B coalesced feature gather, register fp32 accumulate,
//            unroll-8 for 8 gathers in flight per wave.
//            Edge records loaded as u64 (nontemporal builtin rejects
//            HIP_vector_type pointers -- R7 compile lesson).
//            No float atomics anywhere (R4 lesson); no 8x scan (R5 lesson).
// ============================================================================
__global__ __launch_bounds__(256) void partition_kernel(
    const int* __restrict__ u_src, const int* __restrict__ u_dst, const float* __restrict__ u_w,
    const int* __restrict__ i_src, const int* __restrict__ i_dst, const float* __restrict__ i_w,
    int* __restrict__ bcur, uint2* __restrict__ part)
{
    __shared__ int hist[NBUCKET];
    __shared__ int cur[NBUCKET];
    int cs = blockIdx.y;
    const int* srcp; const int* dstp; const float* wp;
    if (cs < NCLASS) {
        srcp = u_src + (size_t)cs * NEDGE;
        dstp = u_dst + (size_t)cs * NEDGE;
        wp   = u_w   + (size_t)cs * NEDGE;
    } else {
        int c = cs - NCLASS;
        srcp = i_src + (size_t)c * NEDGE;
        dstp = i_dst + (size_t)c * NEDGE;
        wp   = i_w   + (size_t)c * NEDGE;
    }
    int lo_e = (int)(((long long)blockIdx.x * NEDGE) / gridDim.x);
    int hi_e = (int)(((long long)(blockIdx.x + 1) * NEDGE) / gridDim.x);

    for (int i = threadIdx.x; i < NBUCKET; i += 256) hist[i] = 0;
    __syncthreads();
    for (int e = lo_e + threadIdx.x; e < hi_e; e += 256)
        atomicAdd(&hist[dstp[e] >> 6], 1);
    __syncthreads();
    for (int i = threadIdx.x; i < NBUCKET; i += 256)
        cur[i] = atomicAdd(&bcur[cs * NBUCKET + i], hist[i]);
    __syncthreads();
    uint2* out = part + (size_t)cs * NBUCKET * CAP;
    for (int e = lo_e + threadIdx.x; e < hi_e; e += 256) {
        int dst = dstp[e];
        int bkt = dst >> 6;
        int pos = atomicAdd(&cur[bkt], 1);
        if (pos < bkt * CAP + CAP)
            out[pos] = make_uint2((unsigned)srcp[e] | ((unsigned)(dst & 63) << 24),
                                  __float_as_uint(wp[e]));
    }
}

__global__ __launch_bounds__(512) void spmm_sorted(
    const u16* __restrict__ item_bf, const u16* __restrict__ user_bf,
    const uint2* __restrict__ part, const int* __restrict__ bcur,
    u16* __restrict__ agg)
{
    __shared__ int hist8[8][BROWS];    // per-wave histograms -> scatter cursors
    __shared__ int bin_off[BROWS + 1];
    __shared__ u16 perm[CAP];
    int b  = blockIdx.x;
    int cs = blockIdx.y;
    const u16* feat = (cs < NCLASS) ? item_bf : user_bf;
    int n = bcur[cs * NBUCKET + b] - b * CAP;
    if (n > CAP) n = CAP;
    const u64* ew64 = (const u64*)(part + ((size_t)cs * NBUCKET + b) * CAP);
    int tid = threadIdx.x, wave = tid >> 6, lane = tid & 63;

    hist8[wave][lane] = 0;
    __syncthreads();
    for (int e = tid; e < n; e += 512) {
        unsigned lo32 = (unsigned)__builtin_nontemporal_load(ew64 + e);
        atomicAdd(&hist8[wave][lo32 >> 24], 1);
    }
    __syncthreads();
    if (tid < BROWS) {
        // per-wave exclusive bases within bin tid (relative), and bin total
        int s = 0;
        int base[8];
        #pragma unroll
        for (int w2 = 0; w2 < 8; ++w2) { base[w2] = s; s += hist8[w2][tid]; }
        // inclusive scan of bin totals across 64 bins (wave 0 shfl)
        int v = s;
        #pragma unroll
        for (int o = 1; o < 64; o <<= 1) {
            int u = __shfl_up(v, o);
            if (lane >= o) v += u;
        }
        bin_off[tid + 1] = v;
        if (tid == 0) bin_off[0] = 0;
        int excl = v - s;
        #pragma unroll
        for (int w2 = 0; w2 < 8; ++w2) hist8[w2][tid] = excl + base[w2];
    }
    __syncthreads();
    for (int e = tid; e < n; e += 512) {
        unsigned lo32 = (unsigned)__builtin_nontemporal_load(ew64 + e);
        int pos = atomicAdd(&hist8[wave][lo32 >> 24], 1);   // per-wave cursor
        perm[pos] = (u16)e;
    }
    __syncthreads();

    int rowbase = cs * NBATCH + b * BROWS;
    #pragma unroll
    for (int r0 = 0; r0 < 8; ++r0) {
        int r = wave * 8 + r0;
        int j0 = bin_off[r], j1 = bin_off[r + 1];
        float ax = 0.f, ay = 0.f, az = 0.f, aw = 0.f;
        int j = j0;
        for (; j + 7 < j1; j += 8) {
            int l[8];
            u64 p[8];
            ushort4 v[8];
            #pragma unroll
            for (int q = 0; q < 8; ++q) l[q] = perm[j + q];
            #pragma unroll
            for (int q = 0; q < 8; ++q) p[q] = __builtin_nontemporal_load(ew64 + l[q]);
            #pragma unroll
            for (int q = 0; q < 8; ++q)
                v[q] = *(const ushort4*)&feat[(size_t)((unsigned)p[q] & 0xFFFFFF) * DFEAT + lane * 4];
            #pragma unroll
            for (int q = 0; q < 8; ++q) {
                float w0 = __uint_as_float((unsigned)(p[q] >> 32));
                ax += w0 * bf2f(v[q].x);
                ay += w0 * bf2f(v[q].y);
                az += w0 * bf2f(v[q].z);
                aw += w0 * bf2f(v[q].w);
            }
        }
        for (; j < j1; ++j) {
            int l0 = perm[j];
            u64 p0 = ew64[l0];
            ushort4 v0 = *(const ushort4*)&feat[(size_t)((unsigned)p0 & 0xFFFFFF) * DFEAT + lane * 4];
            float w0 = __uint_as_float((unsigned)(p0 >> 32));
            ax += w0 * bf2f(v0.x);
            ay += w0 * bf2f(v0.y);
            az += w0 * bf2f(v0.z);
            aw += w0 * bf2f(v0.w);
        }
        ushort4 o4;
        o4.x = f2bf(ax); o4.y = f2bf(ay); o4.z = f2bf(az); o4.w = f2bf(aw);
        *(ushort4*)&agg[(size_t)(rowbase + r) * 256 + lane * 4] = o4;
    }
}

// ============================================================================
// decoder stage 2
// ============================================================================
__global__ __launch_bounds__(256) void decoder_kernel(
    const float* __restrict__ t0, const float* __restrict__ t1,
    const u16* __restrict__ item_emb, const float* __restrict__ Wcomb,
    float* __restrict__ out)
{
    int wave = threadIdx.x >> 6;
    int lane = threadIdx.x & 63;
    int b = blockIdx.x * 4 + wave;
    const u16*   ie = item_emb + (size_t)b * 256;
    const float* p0 = t0 + (size_t)b * 256;
    const float* p1 = t1 + (size_t)b * 256;
    float s0 = 0.f, s1 = 0.f;
    #pragma unroll
    for (int j = lane; j < 256; j += 64) {
        float v = bf2f(ie[j]);
        s0 += p0[j] * v;
        s1 += p1[j] * v;
    }
    #pragma unroll
    for (int o = 32; o > 0; o >>= 1) {
        s0 += __shfl_down(s0, o);
        s1 += __shfl_down(s1, o);
    }
    if (lane == 0) {
        #pragma unroll
        for (int r = 0; r < NCLASS; ++r)
            out[b * NCLASS + r] = Wcomb[r * 2 + 0] * s0 + Wcomb[r * 2 + 1] * s1;
    }
}

// ============================================================================
// launch
// ============================================================================
extern "C" void kernel_launch(void* const* d_in, const int* in_sizes, int n_in,
                              void* d_out, int out_size, void* d_ws, size_t ws_size,
                              hipStream_t stream)
{
    const float* user_feat = (const float*)d_in[0];
    const float* item_feat = (const float*)d_in[1];
    const int*   user_idx  = (const int*)  d_in[2];
    const int*   item_idx  = (const int*)  d_in[3];
    const int*   u_src     = (const int*)  d_in[4];
    const int*   u_dst     = (const int*)  d_in[5];
    const float* u_w       = (const float*)d_in[6];
    const int*   i_src     = (const int*)  d_in[7];
    const int*   i_dst     = (const int*)  d_in[8];
    const float* i_w       = (const float*)d_in[9];
    const float* W_fu      = (const float*)d_in[10];
    const float* b_fu      = (const float*)d_in[11];
    const float* W_fi      = (const float*)d_in[12];
    const float* b_fi      = (const float*)d_in[13];
    const float* W_uc      = (const float*)d_in[14];
    const float* W_ic      = (const float*)d_in[15];
    const float* bn_fu     = (const float*)d_in[16];
    const float* bn_hu     = (const float*)d_in[17];
    const float* bn_fi     = (const float*)d_in[18];
    const float* bn_hi     = (const float*)d_in[19];
    const float* W2_fu     = (const float*)d_in[20];
    const float* W2_hu     = (const float*)d_in[21];
    const float* W2_fi     = (const float*)d_in[22];
    const float* W2_hi     = (const float*)d_in[23];
    const float* Wdec      = (const float*)d_in[24];
    const float* Wcomb     = (const float*)d_in[25];
    float* out = (float*)d_out;

    // ---- workspace layout (193.7 MB) ---------------------------------------
    char* ws = (char*)d_ws;
    int*   bcur       = (int*)  (ws + 0);            // 1280 i32
    uint2* part_ew    = (uint2*)(ws + 65536);        // 47.2 MB (dead after spmm)
    u16*   user_bf    = (u16*)  (ws + 47251456);     // 51.2 MB
    u16*   item_bf    = (u16*)  (ws + 98451456);     // 51.2 MB
    u16*   agg_bf     = (u16*)  (ws + 149651456);    // 41.9 MB (dead after hproj)
    u16*   wT         = (u16*)  (ws + 191594496);    // 2.1 MB
    // overlays on part region (live f-gemm..emb, after spmm):
    u16*   f_user_bf  = (u16*)  (ws + 65536);
    u16*   f_item_bf  = (u16*)  (ws + 4259840);
    u16*   h_user_bf  = (u16*)  (ws + 8454144);
    u16*   h_item_bf  = (u16*)  (ws + 18939904);
    // overlays on agg region (live emb..decoder, after hproj):
    float* t0         = (float*)(ws + 149651456);
    float* t1         = (float*)(ws + 158040064);
    u16*   user_emb   = (u16*)  (ws + 166428672);
    u16*   item_emb   = (u16*)  (ws + 170622976);

    // ---- 1. fused prep (weights T + features bf16 + bcur init) -------------
    cvt_all<<<dim3(4096, 11), 256, 0, stream>>>(
        user_feat, item_feat, user_bf, item_bf,
        W_fu, W_fi, W_uc, W_ic, W2_fu, W2_hu, W2_fi, W2_hi, Wdec, wT, bcur);

    // ---- 2. bucket partition ----------------------------------------------
    partition_kernel<<<dim3(128, 10), 256, 0, stream>>>(
        u_src, u_dst, u_w, i_src, i_dst, i_w, bcur, part_ew);

    // ---- 3. SpMM: privatized counting sort + unroll-8 gather ---------------
    spmm_sorted<<<dim3(NBUCKET, 10), 512, 0, stream>>>(
        item_bf, user_bf, part_ew, bcur, agg_bf);

    // ---- 4. f path (fused user/item) ---------------------------------------
    k_gemm_f<<<dim3(128, 4, 2), 256, 0, stream>>>(
        user_bf, item_bf, user_idx, item_idx, wT + OFF_WFU, wT + OFF_WFI,
        b_fu, b_fi, bn_fu, bn_fi, f_user_bf, f_item_bf);

    // ---- 5. h projection ---------------------------------------------------
    k_hproj<<<dim3(128, 2, 10), 256, 0, stream>>>(agg_bf, wT + OFF_WUC, wT + OFF_WIC,
                                                  bn_hu, bn_hi, h_user_bf, h_item_bf);

    // ---- 6. embeddings (fused user/item) -----------------------------------
    k_emb<<<dim3(128, 4, 2), 256, 0, stream>>>(
        f_user_bf, f_item_bf, h_user_bf, h_item_bf,
        wT + OFF_W2FU, wT + OFF_W2HU, wT + OFF_W2FI, wT + OFF_W2HI,
        user_emb, item_emb);

    // ---- 7. decoder ---------------------------------------------------------
    k_dec<<<dim3(128, 4, 2), 256, 0, stream>>>(user_emb, wT + OFF_WDEC, t0, t1);
    decoder_kernel<<<NBATCH / 4, 256, 0, stream>>>(t0, t1, item_emb, Wcomb, out);
}